// Round 13
// baseline (2690.981 us; speedup 1.0000x reference)
//
#include <hip/hip_runtime.h>
#include <hip/hip_bf16.h>

// LSTM surrogate: B=256, T=512, D=256, U=512, O=64.
// R13 = R12 base (proven 2580us protocol/structure) minus serial work:
//  (1) y-decode fused into gates pass as 4 MFMAs/wave (K-split), Wd as bf16
//      B-frags, partials in tiny LDS, summed by wave2 in pointwise phase
//  (2) packed bf16 cvt (v_cvt_pk_bf16_f32 via __float22bfloat162_rn)
//  (3) x_{t+1} prefetched to registers at step top (s1 vmcnt drain hides HBM)
//  (4) barrier s3 dropped (window || poll independent) -> 4 barriers/step
// 16 batch-groups x 16 rows, 32 unit-groups -> grid 512, 2 blocks/CU.

#define Bb 256
#define Tt 512
#define Dd 256
#define Uu 512
#define Oo 64

typedef short bs8 __attribute__((ext_vector_type(8)));      // 8 bf16 (bits)
typedef float f32x4 __attribute__((ext_vector_type(4)));

__device__ __forceinline__ unsigned short f2bf(float f) {
  unsigned u = __float_as_uint(f);
  u += 0x7fffu + ((u >> 16) & 1u);                          // RNE
  return (unsigned short)(u >> 16);
}
__device__ __forceinline__ unsigned f2bf2(float lo, float hi) {
  union { __hip_bfloat162 b; unsigned u; } cv;
  cv.b = __float22bfloat162_rn(make_float2(lo, hi));        // v_cvt_pk_bf16_f32
  return cv.u;
}
__device__ __forceinline__ float sigm(float v) { return 1.0f / (1.0f + __expf(-v)); }
__device__ __forceinline__ float tanhfast(float v) { return 2.0f / (1.0f + __expf(-2.0f * v)) - 1.0f; }

// z LDS: [16 rows][768 k] bf16, row stride 1536 B. XOR swizzle on 16B granules.
__device__ __forceinline__ int zbyte(int row, int k) {
  return (row * 1536 + k * 2) ^ ((row & 7) << 4);
}

// flags: group g, block i -> bar[(g*32 + i)*32]  (one 128B line per flag)
__global__ void rnn_init_bar(unsigned* bar) {
  for (int i = threadIdx.x; i < 16 * 32 * 32; i += 256)
    __hip_atomic_store(&bar[i], 0u, __ATOMIC_RELAXED, __HIP_MEMORY_SCOPE_AGENT);
}

__launch_bounds__(256, 2)
__global__ void rnn_lstm_kernel(const float* __restrict__ x, const float* __restrict__ Wx,
                                const float* __restrict__ Wh, const float* __restrict__ bias,
                                const float* __restrict__ Wd, const float* __restrict__ bd,
                                float* __restrict__ out, unsigned short* hbuf, unsigned* bar) {
  __shared__ __align__(16) char zs[16 * 768 * 2];   // 24576 B
  __shared__ float gates[4][16][17];                // [gate][row][unit], pad
  __shared__ float yp[4][16][2];                    // y partials [wave][row][oc]

  const int tid = threadIdx.x;
  const int lane = tid & 63;
  const int wid = tid >> 6;                         // wave 0..3 == gate id
  const int bid = blockIdx.x;
  const int bg = (bid & 7) | ((bid >> 8) << 3);     // 0..15 (XCD-affine heuristic)
  const int ug = (bid >> 3) & 31;                   // 0..31
  const int b_base = bg * 16;
  const int u_base = ug * 16;
  const int oc0 = ug * 2;

  unsigned* fl = bar + bg * 32 * 32;  // 32 flags, each on its own 128B line

  // ---- gate-weight slice as B-fragments: wave w = gate w; col=lane&15 ----
  bs8 breg[24];
  {
    const int gc = wid * 512 + u_base + (lane & 15);
    const int kfr = (lane >> 4) * 8;
#pragma unroll
    for (int ks = 0; ks < 24; ++ks) {
      bs8 bb;
#pragma unroll
      for (int e = 0; e < 8; ++e) {
        int kg = ks * 32 + kfr + e;
        float w = (kg < 256) ? Wx[(size_t)kg * 2048 + gc]
                             : Wh[(size_t)(kg - 256) * 2048 + gc];
        bb[e] = (short)f2bf(w);
      }
      breg[ks] = bb;
    }
  }
  // ---- Wd slice as bf16 B-frags (y fused GEMM): wave w takes ks 8+4w..8+4w+3 ----
  // B-frag col = lane&15 (only cols 0,1 = out cols oc0,oc0+1; rest zero weights)
  bs8 wdfrag[4];
  {
    const int col = lane & 15;
    const int kfr = (lane >> 4) * 8;
#pragma unroll
    for (int i = 0; i < 4; ++i) {
      int ksl = wid * 4 + i;                         // 0..15 over units/32
      bs8 bb;
#pragma unroll
      for (int e = 0; e < 8; ++e) {
        int u = ksl * 32 + kfr + e;                  // unit 0..511
        bb[e] = (col < 2) ? (short)f2bf(Wd[(size_t)u * Oo + oc0 + col]) : (short)0;
      }
      wdfrag[i] = bb;
    }
  }

  // pointwise ownership (tid<64): row = tid&15, us4 = tid>>4 (0..3), units us4*4+{0..3}
  const int prow = tid & 15;
  const int us4 = (tid >> 4) & 3;
  float bi[4], bff[4], bgg[4], boo[4];
  if (tid < 64) {
#pragma unroll
    for (int j = 0; j < 4; ++j) {
      int ugl = u_base + us4 * 4 + j;
      bi[j]  = bias[0 * 512 + ugl];
      bff[j] = bias[1 * 512 + ugl];
      bgg[j] = bias[2 * 512 + ugl];
      boo[j] = bias[3 * 512 + ugl];
    }
  }
  float cst[4] = {0.f, 0.f, 0.f, 0.f};

  union U16 { unsigned long long q[2]; bs8 v; };

  // ---- prologue: stage x_0, zero h-region ----
  {
    int row = tid >> 4;
    int d0 = (tid & 15) * 16;
    const float* xp = x + ((size_t)(b_base + row) * Tt + 0) * Dd + d0;
    float4 v0 = *(const float4*)xp;
    float4 v1 = *(const float4*)(xp + 4);
    float4 v2 = *(const float4*)(xp + 8);
    float4 v3 = *(const float4*)(xp + 12);
    uint4 p0, p1;
    p0.x = f2bf2(v0.x, v0.y); p0.y = f2bf2(v0.z, v0.w);
    p0.z = f2bf2(v1.x, v1.y); p0.w = f2bf2(v1.z, v1.w);
    p1.x = f2bf2(v2.x, v2.y); p1.y = f2bf2(v2.z, v2.w);
    p1.z = f2bf2(v3.x, v3.y); p1.w = f2bf2(v3.z, v3.w);
    *(uint4*)(zs + zbyte(row, d0)) = p0;
    *(uint4*)(zs + zbyte(row, d0 + 8)) = p1;
  }
#pragma unroll
  for (int i = 0; i < 4; ++i) {
    int c = tid + i * 256;
    int row = c >> 6;
    int u0 = (c & 63) * 8;
    bs8 zz = {0, 0, 0, 0, 0, 0, 0, 0};
    *(bs8*)(zs + zbyte(row, 256 + u0)) = zz;
  }
  __syncthreads();

  const int arow = lane & 15;
  const int akf = (lane >> 4) * 8;
  const int rb = (lane >> 4) * 4;

  for (int t = 0; t < Tt; ++t) {
    // ---- prefetch x_{t+1} to registers (latency hidden by MFMA + s1 drain) ----
    float4 xv0, xv1, xv2, xv3;
    const int xrow = tid >> 4;
    const int xd0 = (tid & 15) * 16;
    if (t + 1 < Tt) {
      const float* xp = x + ((size_t)(b_base + xrow) * Tt + (t + 1)) * Dd + xd0;
      xv0 = *(const float4*)xp;
      xv1 = *(const float4*)(xp + 4);
      xv2 = *(const float4*)(xp + 8);
      xv3 = *(const float4*)(xp + 12);
    }

    // ---- gates MFMA: wave's gate [16 rows x 16 units], K=768 ----
    f32x4 acc0 = {0, 0, 0, 0}, acc1 = {0, 0, 0, 0};
#pragma unroll
    for (int ks = 0; ks < 24; ks += 2) {
      bs8 av0 = *(const bs8*)(zs + zbyte(arow, ks * 32 + akf));
      bs8 av1 = *(const bs8*)(zs + zbyte(arow, (ks + 1) * 32 + akf));
      acc0 = __builtin_amdgcn_mfma_f32_16x16x32_bf16(av0, breg[ks], acc0, 0, 0, 0);
      acc1 = __builtin_amdgcn_mfma_f32_16x16x32_bf16(av1, breg[ks + 1], acc1, 0, 0, 0);
    }
    acc0 += acc1;
    // ---- fused y MFMA: y_{t-1} partial = h_{t-1} @ Wd (K-split by wave) ----
    {
      f32x4 yacc = {0, 0, 0, 0};
#pragma unroll
      for (int i = 0; i < 4; ++i) {
        int ks = 8 + wid * 4 + i;
        bs8 av = *(const bs8*)(zs + zbyte(arow, ks * 32 + akf));
        yacc = __builtin_amdgcn_mfma_f32_16x16x32_bf16(av, wdfrag[i], yacc, 0, 0, 0);
      }
      if ((lane & 15) < 2) {
#pragma unroll
        for (int j = 0; j < 4; ++j) yp[wid][rb + j][lane & 15] = yacc[j];
      }
    }
    // C/D (HW-verified): col = lane&15, row = (lane>>4)*4 + reg
    {
      const int u16 = lane & 15;
#pragma unroll
      for (int j = 0; j < 4; ++j) gates[wid][rb + j][u16] = acc0[j];
    }
    __syncthreads();                                        // s1

    // ---- pointwise (w0) || y sum+store (w2, t>0) ----
    if (tid < 64) {
      float hv[4];
#pragma unroll
      for (int j = 0; j < 4; ++j) {
        int u = us4 * 4 + j;
        float gi = gates[0][prow][u] + bi[j];
        float gf = gates[1][prow][u] + bff[j];
        float gg = gates[2][prow][u] + bgg[j];
        float go = gates[3][prow][u] + boo[j];
        float iv = sigm(gi), fv = sigm(gf), gv = tanhfast(gg), ov = sigm(go);
        float cn = fv * cst[j] + iv * gv;
        cst[j] = cn;
        hv[j] = ov * tanhfast(cn);
      }
      unsigned long long hpack =
          (unsigned long long)f2bf2(hv[0], hv[1]) |
          ((unsigned long long)f2bf2(hv[2], hv[3]) << 32);
      unsigned long long* hp =
          (unsigned long long*)(hbuf + (size_t)(t & 1) * Bb * Uu +
                                (size_t)(b_base + prow) * Uu + u_base + us4 * 4);
      unsigned long long old = __hip_atomic_exchange(hp, hpack, __ATOMIC_RELAXED,
                                                     __HIP_MEMORY_SCOPE_AGENT);
      asm volatile("" :: "v"(old));   // keep the returning (executes-at-L3) form
    } else if (t > 0 && tid >= 128 && tid < 160) {
      int b = (tid - 128) >> 1, oc = tid & 1;
      float s = bd[oc0 + oc] + yp[0][b][oc] + yp[1][b][oc] + yp[2][b][oc] + yp[3][b][oc];
      out[((size_t)(b_base + b) * Tt + (t - 1)) * Oo + oc0 + oc] = s;
    }
    // barrier drains each wave's vmcnt: all h-swaps have EXECUTED AT L3 here.
    __syncthreads();                                        // s2
    if (tid == 0) {
      unsigned oldf = __hip_atomic_exchange(&fl[ug * 32], (unsigned)(t + 1),
                                            __ATOMIC_RELAXED, __HIP_MEMORY_SCOPE_AGENT);
      asm volatile("" :: "v"(oldf));
    }

    // ---- window: x_{t+1} cvt+write from prefetched regs (all waves) ----
    if (t + 1 < Tt) {
      uint4 p0, p1;
      p0.x = f2bf2(xv0.x, xv0.y); p0.y = f2bf2(xv0.z, xv0.w);
      p0.z = f2bf2(xv1.x, xv1.y); p0.w = f2bf2(xv1.z, xv1.w);
      p1.x = f2bf2(xv2.x, xv2.y); p1.y = f2bf2(xv2.z, xv2.w);
      p1.z = f2bf2(xv3.x, xv3.y); p1.w = f2bf2(xv3.z, xv3.w);
      *(uint4*)(zs + zbyte(xrow, xd0)) = p0;
      *(uint4*)(zs + zbyte(xrow, xd0 + 8)) = p1;
    }
    // ---- poll (wave1, after its x share; no barrier needed before) ----
    if (wid == 1) {
      for (;;) {
        unsigned v = __hip_atomic_load(&fl[(lane & 31) * 32], __ATOMIC_RELAXED,
                                       __HIP_MEMORY_SCOPE_AGENT);
        if (!__any((int)(v < (unsigned)(t + 1)))) break;
        __builtin_amdgcn_s_sleep(2);
      }
    }
    __builtin_amdgcn_sched_barrier(0);
    __syncthreads();                                        // s4 (poll gate)

    // ---- stage h_t from hbuf[t&1] (bulk, coalesced, all loads in flight) ----
    {
      const unsigned short* hsrc = hbuf + (size_t)(t & 1) * Bb * Uu;
#pragma unroll
      for (int i = 0; i < 4; ++i) {
        int c = tid + i * 256;
        int row = c >> 6;
        int u0 = (c & 63) * 8;
        const unsigned long long* p =
            (const unsigned long long*)(hsrc + (size_t)(b_base + row) * Uu + u0);
        U16 uu;
        uu.q[0] = __hip_atomic_load(p, __ATOMIC_RELAXED, __HIP_MEMORY_SCOPE_AGENT);
        uu.q[1] = __hip_atomic_load(p + 1, __ATOMIC_RELAXED, __HIP_MEMORY_SCOPE_AGENT);
        *(bs8*)(zs + zbyte(row, 256 + u0)) = uu.v;
      }
    }
    __syncthreads();                                        // s5
  }

  // ---- epilogue: y_{T-1} via the same fused MFMA on final zs.h ----
  {
    f32x4 yacc = {0, 0, 0, 0};
#pragma unroll
    for (int i = 0; i < 4; ++i) {
      int ks = 8 + wid * 4 + i;
      bs8 av = *(const bs8*)(zs + zbyte(arow, ks * 32 + akf));
      yacc = __builtin_amdgcn_mfma_f32_16x16x32_bf16(av, wdfrag[i], yacc, 0, 0, 0);
    }
    if ((lane & 15) < 2) {
#pragma unroll
      for (int j = 0; j < 4; ++j) yp[wid][rb + j][lane & 15] = yacc[j];
    }
    __syncthreads();
    if (tid < 32) {
      int b = tid >> 1, oc = tid & 1;
      float s = bd[oc0 + oc] + yp[0][b][oc] + yp[1][b][oc] + yp[2][b][oc] + yp[3][b][oc];
      out[((size_t)(b_base + b) * Tt + (Tt - 1)) * Oo + oc0 + oc] = s;
    }
  }
}

extern "C" void kernel_launch(void* const* d_in, const int* in_sizes, int n_in,
                              void* d_out, int out_size, void* d_ws, size_t ws_size,
                              hipStream_t stream) {
  const float* x  = (const float*)d_in[0];
  const float* Wx = (const float*)d_in[1];
  const float* Wh = (const float*)d_in[2];
  const float* bs = (const float*)d_in[3];
  const float* Wd = (const float*)d_in[4];
  const float* bd = (const float*)d_in[5];
  float* out = (float*)d_out;

  unsigned short* hbuf = (unsigned short*)d_ws;                       // 2*256*512 bf16 = 512 KiB
  unsigned* bar = (unsigned*)((char*)d_ws + (size_t)2 * Bb * Uu * 2); // 16g * 32 flags * 128B

  rnn_init_bar<<<1, 256, 0, stream>>>(bar);
  rnn_lstm_kernel<<<dim3(512), dim3(256), 0, stream>>>(x, Wx, Wh, bs, Wd, bd, out, hbuf, bar);
}